// Round 1
// baseline (98.177 us; speedup 1.0000x reference)
//
#include <hip/hip_runtime.h>
#include <hip/hip_bf16.h>

#define N_NODES 100000
#define HID 128
#define BB 64
#define CC 16
#define LL 256
#define NK 4
#define BC (BB * CC)

typedef __bf16 b16x8 __attribute__((ext_vector_type(8)));
typedef float f32x4 __attribute__((ext_vector_type(4)));

__device__ __forceinline__ unsigned int bf16pair(float a, float b) {
  unsigned int ua = __float_as_uint(a), ub = __float_as_uint(b);
  ua = (ua + 0x7FFFu + ((ua >> 16) & 1u)) >> 16;
  ub = (ub + 0x7FFFu + ((ub >> 16) & 1u)) >> 16;
  return ua | (ub << 16);
}

__device__ __forceinline__ float elu(float v) {
  return v > 0.f ? v : (__expf(v) - 1.f);
}

// ---------------------------------------------------------------------------
// Prep: W_z [4][128][128] f32 -> bf16 fragment-linear layout.
// Element u (uint4 index): u = ((kk*4 + ks)*8 + ot)*64 + lane
//   holds W_z[ks][o][h0..h0+7], o = ot*16 + (lane&15), h0 = kk*32 + (lane>>4)*8
// ---------------------------------------------------------------------------
__global__ void k_prep(const float* __restrict__ Wz, uint4* __restrict__ wfrag) {
  const int u = blockIdx.x * 256 + threadIdx.x;  // 8192 threads
  const int lane = u & 63;
  const int ot = (u >> 6) & 7;
  const int ks = (u >> 9) & 3;
  const int kk = u >> 11;
  const int o = ot * 16 + (lane & 15);
  const int h0 = kk * 32 + (lane >> 4) * 8;
  const float4* src = (const float4*)(Wz + ((size_t)(ks * HID + o) * HID + h0));
  float4 f0 = src[0], f1 = src[1];
  uint4 pk;
  pk.x = bf16pair(f0.x, f0.y);
  pk.y = bf16pair(f0.z, f0.w);
  pk.z = bf16pair(f1.x, f1.y);
  pk.w = bf16pair(f1.z, f1.w);
  wfrag[u] = pk;
}

// ---------------------------------------------------------------------------
// Main: one WG per (b,c). 8 waves, each owns output rows [w*32, w*32+32) x 128 cols.
// LDS: sA = data tile 256x128 bf16, XOR-swizzled ((row&15)<<4).
//      sB = double-buffered weight K-slice (32KB each), fragment-linear.
// z_pre[l][o] = sum_ks sum_h data[(l+ks)&255][h] * W_z[ks][o][h]
// Emits zsum[bc][o] = sum_l elu(z_pre[l][o]).
// ---------------------------------------------------------------------------
__global__ __launch_bounds__(512, 2) void k_main(
    const float* __restrict__ x, const int* __restrict__ leaf_idx,
    const uint4* __restrict__ wfrag, float* __restrict__ zsum) {
  extern __shared__ char smem[];
  char* sA = smem;                               // 65536 B
  uint4* sB0 = (uint4*)(smem + 65536);           // 2 x 2048 uint4 = 65536 B

  const int tid = threadIdx.x;
  const int bc = blockIdx.x;
  const int lane = tid & 63;
  const int w = tid >> 6;

  // ---- stage data tile (gather + f32->bf16 + swizzled LDS write) ----
  {
    const int r = tid >> 1, half = tid & 1;
    const int idx = leaf_idx[bc * LL + r];
    const float4* src = (const float4*)(x + (size_t)idx * HID + half * 64);
    const int swz = (r & 15) << 4;
    char* rowp = sA + r * 256;
#pragma unroll
    for (int j = 0; j < 8; ++j) {
      float4 f0 = src[2 * j];
      float4 f1 = src[2 * j + 1];
      uint4 pk;
      pk.x = bf16pair(f0.x, f0.y);
      pk.y = bf16pair(f0.z, f0.w);
      pk.z = bf16pair(f1.x, f1.y);
      pk.w = bf16pair(f1.z, f1.w);
      *(uint4*)(rowp + (((half * 128) + j * 16) ^ swz)) = pk;
    }
  }
  // ---- stage weight slice 0 (contiguous copy, 64B/thread) ----
  {
    const uint4* g = wfrag + tid * 4;
#pragma unroll
    for (int i = 0; i < 4; ++i) sB0[tid * 4 + i] = g[i];
  }
  __syncthreads();

  f32x4 acc[2][8];
#pragma unroll
  for (int rt = 0; rt < 2; ++rt)
#pragma unroll
    for (int ot = 0; ot < 8; ++ot) acc[rt][ot] = (f32x4){0.f, 0.f, 0.f, 0.f};

  const int r0 = w * 32;
  uint4 pref[4];

#pragma unroll
  for (int kk = 0; kk < 4; ++kk) {
    const int cur = kk & 1;
    // prefetch next weight slice into registers (hides L2 latency under MFMA)
    if (kk < 3) {
      const uint4* g = wfrag + (kk + 1) * 2048 + tid * 4;
#pragma unroll
      for (int i = 0; i < 4; ++i) pref[i] = g[i];
    }
    const int cb = kk * 64 + (lane >> 4) * 16;  // 16B chunk offset within row
#pragma unroll
    for (int ks = 0; ks < NK; ++ks) {
      uint4 af[2];
#pragma unroll
      for (int rt = 0; rt < 2; ++rt) {
        const int row = (r0 + rt * 16 + (lane & 15) + ks) & 255;
        af[rt] = *(const uint4*)(sA + row * 256 + (cb ^ ((row & 15) << 4)));
      }
#pragma unroll
      for (int ot = 0; ot < 8; ++ot) {
        const uint4 bw = sB0[cur * 2048 + (ks * 8 + ot) * 64 + lane];
        const b16x8 bb = __builtin_bit_cast(b16x8, bw);
        acc[0][ot] = __builtin_amdgcn_mfma_f32_16x16x32_bf16(
            __builtin_bit_cast(b16x8, af[0]), bb, acc[0][ot], 0, 0, 0);
        acc[1][ot] = __builtin_amdgcn_mfma_f32_16x16x32_bf16(
            __builtin_bit_cast(b16x8, af[1]), bb, acc[1][ot], 0, 0, 0);
      }
    }
    // write prefetched slice to the other buffer
    if (kk < 3) {
#pragma unroll
      for (int i = 0; i < 4; ++i) sB0[(cur ^ 1) * 2048 + tid * 4 + i] = pref[i];
    }
    __syncthreads();
  }

  // ---- epilogue: elu + sum over this wave's 32 rows, then cross-wave reduce ----
  // C/D layout (16x16x32): col o = ot*16 + (lane&15); row = rt*16 + (lane>>4)*4 + q
  float colsum[8];
#pragma unroll
  for (int ot = 0; ot < 8; ++ot) {
    float s = 0.f;
#pragma unroll
    for (int rt = 0; rt < 2; ++rt)
#pragma unroll
      for (int q = 0; q < 4; ++q) s += elu(acc[rt][ot][q]);
    s += __shfl_xor(s, 16);
    s += __shfl_xor(s, 32);
    colsum[ot] = s;
  }
  float* sRed = (float*)(smem + 65536);  // reuse sB[0] region (not read in last phase)
  if (lane < 16) {
#pragma unroll
    for (int ot = 0; ot < 8; ++ot) sRed[w * 128 + ot * 16 + lane] = colsum[ot];
  }
  __syncthreads();
  if (tid < 128) {
    float s = 0.f;
#pragma unroll
    for (int ww = 0; ww < 8; ++ww) s += sRed[ww * 128 + tid];
    zsum[bc * 128 + tid] = s;
  }
}

// ---------------------------------------------------------------------------
// Tail (f32, exact): z2 = elu(zsum @ Wzf^T); s = sum_c z2; p = s @ Wp^T;
// out = p @ Wpf^T.  One block per b.
// ---------------------------------------------------------------------------
__global__ __launch_bounds__(256) void k_tail(
    const float* __restrict__ zsum, const float* __restrict__ Wzf,
    const float* __restrict__ Wp, const float* __restrict__ Wpf,
    float* __restrict__ out) {
  __shared__ float sZ[CC * HID];
  __shared__ float sS2[2][HID];
  __shared__ float sP[HID];
  const int tid = threadIdx.x;
  const int b = blockIdx.x;
#pragma unroll
  for (int j = 0; j < 8; ++j) sZ[tid + j * 256] = zsum[b * (CC * HID) + tid + j * 256];
  __syncthreads();
  const int o = tid & 127, g = tid >> 7;
  const float4* wr = (const float4*)(Wzf + o * HID);
  float part = 0.f;
#pragma unroll
  for (int cj = 0; cj < 8; ++cj) {
    const int c = g * 8 + cj;
    const float4* zr = (const float4*)(sZ + c * HID);
    float d = 0.f;
#pragma unroll 8
    for (int h4 = 0; h4 < 32; ++h4) {
      float4 wv = wr[h4];
      float4 zv = zr[h4];
      d += wv.x * zv.x + wv.y * zv.y + wv.z * zv.z + wv.w * zv.w;
    }
    part += elu(d);
  }
  sS2[g][o] = part;
  __syncthreads();
  if (tid < 128) sZ[tid] = sS2[0][tid] + sS2[1][tid];  // s vector, reuse sZ
  __syncthreads();
  if (tid < 128) {
    const float4* wpr = (const float4*)(Wp + tid * HID);
    const float4* sv = (const float4*)sZ;
    float d = 0.f;
#pragma unroll 8
    for (int h4 = 0; h4 < 32; ++h4) {
      float4 wv = wpr[h4];
      float4 zv = sv[h4];
      d += wv.x * zv.x + wv.y * zv.y + wv.z * zv.z + wv.w * zv.w;
    }
    sP[tid] = d;
  }
  __syncthreads();
  if (tid < 128) {
    const float4* wpr = (const float4*)(Wpf + tid * HID);
    const float4* pv = (const float4*)sP;
    float d = 0.f;
#pragma unroll 8
    for (int h4 = 0; h4 < 32; ++h4) {
      float4 wv = wpr[h4];
      float4 pvv = pv[h4];
      d += wv.x * pvv.x + wv.y * pvv.y + wv.z * pvv.z + wv.w * pvv.w;
    }
    out[b * HID + tid] = d;
  }
}

extern "C" void kernel_launch(void* const* d_in, const int* in_sizes, int n_in,
                              void* d_out, int out_size, void* d_ws, size_t ws_size,
                              hipStream_t stream) {
  const float* x = (const float*)d_in[0];
  const int* leaf = (const int*)d_in[1];
  const float* Wz = (const float*)d_in[2];
  const float* Wzf = (const float*)d_in[3];
  const float* Wp = (const float*)d_in[4];
  const float* Wpf = (const float*)d_in[5];
  float* out = (float*)d_out;

  uint4* wfrag = (uint4*)d_ws;                       // 128 KB
  float* zsum = (float*)((char*)d_ws + 131072);      // 512 KB

  (void)hipFuncSetAttribute((const void*)k_main,
                            hipFuncAttributeMaxDynamicSharedMemorySize, 131072);

  k_prep<<<32, 256, 0, stream>>>(Wz, wfrag);
  k_main<<<1024, 512, 131072, stream>>>(x, leaf, wfrag, zsum);
  k_tail<<<64, 256, 0, stream>>>(zsum, Wzf, Wp, Wpf, out);
}